// Round 1
// baseline (1798.251 us; speedup 1.0000x reference)
//
#include <hip/hip_runtime.h>
#include <hip/hip_bf16.h>

// ---------------------------------------------------------------------------
// GCN 4-layer inference, fp32 baseline.
// Pipeline per layer: h = a_prev @ W^T  (gemm), then CSR gather-aggregate
// with symmetric norm, + bias, (+ReLU).  CSR (by dst) built per call.
// ---------------------------------------------------------------------------

#define DEV_INLINE __device__ __forceinline__

// ---------------- CSR build ----------------

__global__ void k_init(int* __restrict__ cnt, int* __restrict__ fill, int n) {
    int i = blockIdx.x * 256 + threadIdx.x;
    if (i < n) { cnt[i] = 1; fill[i] = 0; }   // 1 = self-loop
}

__global__ void k_count(const int* __restrict__ dst, int* __restrict__ cnt, int E) {
    int e = blockIdx.x * 256 + threadIdx.x;
    if (e < E) atomicAdd(&cnt[dst[e]], 1);
}

__global__ void k_dinv(const int* __restrict__ cnt, float* __restrict__ dinv, int n) {
    int i = blockIdx.x * 256 + threadIdx.x;
    if (i < n) dinv[i] = rsqrtf((float)cnt[i]);   // cnt >= 1 always (self-loop)
}

// block scans 1024 elements (256 thr x 4), writes exclusive-within-chunk
__global__ void k_scan1(const int* __restrict__ cnt, int* __restrict__ row_start,
                        int* __restrict__ partial, int n) {
    __shared__ int sdata[256];
    int base = blockIdx.x * 1024;
    int t = threadIdx.x;
    int v[4]; int sum = 0;
#pragma unroll
    for (int j = 0; j < 4; ++j) {
        int idx = base + t * 4 + j;
        v[j] = (idx < n) ? cnt[idx] : 0;
        sum += v[j];
    }
    sdata[t] = sum;
    __syncthreads();
    for (int off = 1; off < 256; off <<= 1) {
        int x = (t >= off) ? sdata[t - off] : 0;
        __syncthreads();
        sdata[t] += x;
        __syncthreads();
    }
    int excl = sdata[t] - sum;
#pragma unroll
    for (int j = 0; j < 4; ++j) {
        int idx = base + t * 4 + j;
        if (idx < n) row_start[idx] = excl;
        excl += v[j];
    }
    if (t == 255) partial[blockIdx.x] = sdata[255];
}

__global__ void k_scan2(int* __restrict__ partial, int nb) {
    __shared__ int s[128];
    int t = threadIdx.x;
    int v = (t < nb) ? partial[t] : 0;
    s[t] = v;
    __syncthreads();
    for (int off = 1; off < 128; off <<= 1) {
        int x = (t >= off) ? s[t - off] : 0;
        __syncthreads();
        s[t] += x;
        __syncthreads();
    }
    if (t < nb) partial[t] = s[t] - v;   // exclusive
}

__global__ void k_scan3(int* __restrict__ row_start, const int* __restrict__ partial,
                        int n, int total) {
    int i = blockIdx.x * 256 + threadIdx.x;
    if (i < n) row_start[i] += partial[i >> 10];
    if (i == 0) row_start[n] = total;
}

__global__ void k_fill(const int* __restrict__ src, const int* __restrict__ dst,
                       const float* __restrict__ dinv, const int* __restrict__ row_start,
                       int* __restrict__ fill, int* __restrict__ csr_src,
                       float* __restrict__ csr_norm, int E, int n) {
    int i = blockIdx.x * 256 + threadIdx.x;
    int total = E + n;
    if (i >= total) return;
    int s, d;
    if (i < E) { s = src[i]; d = dst[i]; }
    else       { s = d = i - E; }
    int pos = row_start[d] + atomicAdd(&fill[d], 1);
    csr_src[pos]  = s;
    csr_norm[pos] = dinv[s] * dinv[d];
}

// ---------------- GEMM:  C[m][n] = sum_k A[m*K+k] * B[n*K+k]  ----------------
// A: [M,K] row-major, B: [N,K] row-major (i.e. W as given, out = A @ B^T)

__global__ __launch_bounds__(256) void gemm_nt(const float* __restrict__ A,
                                               const float* __restrict__ B,
                                               float* __restrict__ C,
                                               int M, int N, int K) {
    const int BM = 64, BN = 64, BK = 32;
    __shared__ float As[BK][BM + 1];
    __shared__ float Bs[BK][BN + 1];
    int t  = threadIdx.x;
    int m0 = blockIdx.x * BM;
    int n0 = blockIdx.y * BN;
    int r0 = (t >> 4) * 4;
    int c0 = (t & 15) * 4;
    float acc[4][4] = {};
    for (int kb = 0; kb < K; kb += BK) {
#pragma unroll
        for (int j = 0; j < 8; ++j) {
            int idx = t + j * 256;     // 0..2047
            int r = idx >> 5;          // 0..63
            int k = idx & 31;
            int gk = kb + k;
            int gm = m0 + r;
            As[k][r] = (gm < M && gk < K) ? A[(size_t)gm * K + gk] : 0.f;
            int gn = n0 + r;
            Bs[k][r] = (gn < N && gk < K) ? B[(size_t)gn * K + gk] : 0.f;
        }
        __syncthreads();
#pragma unroll
        for (int k = 0; k < BK; ++k) {
            float a[4], b[4];
#pragma unroll
            for (int j = 0; j < 4; ++j) a[j] = As[k][r0 + j];
#pragma unroll
            for (int j = 0; j < 4; ++j) b[j] = Bs[k][c0 + j];
#pragma unroll
            for (int i = 0; i < 4; ++i)
#pragma unroll
                for (int j = 0; j < 4; ++j)
                    acc[i][j] += a[i] * b[j];
        }
        __syncthreads();
    }
#pragma unroll
    for (int i = 0; i < 4; ++i) {
        int gm = m0 + r0 + i;
        if (gm >= M) continue;
#pragma unroll
        for (int j = 0; j < 4; ++j) {
            int gn = n0 + c0 + j;
            if (gn < N) C[(size_t)gm * N + gn] = acc[i][j];
        }
    }
}

// tiny GEMM for the last layer (N=3, K=40): one thread per row
__global__ void gemm_small(const float* __restrict__ A, const float* __restrict__ B,
                           float* __restrict__ C, int M, int N, int K) {
    int m = blockIdx.x * 256 + threadIdx.x;
    if (m >= M) return;
    float acc0 = 0.f, acc1 = 0.f, acc2 = 0.f;
    for (int k = 0; k < K; ++k) {
        float a = A[(size_t)m * K + k];
        acc0 += a * B[0 * K + k];
        acc1 += a * B[1 * K + k];
        acc2 += a * B[2 * K + k];
    }
    C[(size_t)m * 3 + 0] = acc0;
    C[(size_t)m * 3 + 1] = acc1;
    C[(size_t)m * 3 + 2] = acc2;
}

// ---------------- Aggregation: out[i] = sum_e norm_e * h[src_e]  + b ----------------
// one wave (64 lanes) per node, lanes cover feature chunks of 64

template <int F, bool RELU>
__global__ __launch_bounds__(256) void agg_wave(const float* __restrict__ h,
                                                const int* __restrict__ row_start,
                                                const int* __restrict__ csr_src,
                                                const float* __restrict__ csr_norm,
                                                const float* __restrict__ bias,
                                                float* __restrict__ out, int n) {
    int wave = blockIdx.x * (blockDim.x >> 6) + (threadIdx.x >> 6);
    int lane = threadIdx.x & 63;
    if (wave >= n) return;
    constexpr int NC = (F + 63) / 64;
    float acc[NC];
#pragma unroll
    for (int c = 0; c < NC; ++c) acc[c] = 0.f;
    int e0 = row_start[wave], e1 = row_start[wave + 1];
    for (int e = e0; e < e1; ++e) {
        int   s = csr_src[e];
        float w = csr_norm[e];
#pragma unroll
        for (int c = 0; c < NC; ++c) {
            int f = c * 64 + lane;
            if (f < F) acc[c] += h[(size_t)s * F + f] * w;
        }
    }
#pragma unroll
    for (int c = 0; c < NC; ++c) {
        int f = c * 64 + lane;
        if (f < F) {
            float v = acc[c] + bias[f];
            if (RELU) v = fmaxf(v, 0.f);
            out[(size_t)wave * F + f] = v;
        }
    }
}

// small-F aggregation: one thread per (node, feature)
template <int F>
__global__ void agg_tpf(const float* __restrict__ h, const int* __restrict__ row_start,
                        const int* __restrict__ csr_src, const float* __restrict__ csr_norm,
                        const float* __restrict__ bias, float* __restrict__ out, int n) {
    int i = blockIdx.x * blockDim.x + threadIdx.x;
    if (i >= n * F) return;
    int node = i / F;
    int f = i - node * F;
    float acc = 0.f;
    int e1 = row_start[node + 1];
    for (int e = row_start[node]; e < e1; ++e)
        acc += h[(size_t)csr_src[e] * F + f] * csr_norm[e];
    out[i] = acc + bias[f];
}

// ---------------------------------------------------------------------------

extern "C" void kernel_launch(void* const* d_in, const int* in_sizes, int n_in,
                              void* d_out, int out_size, void* d_ws, size_t ws_size,
                              hipStream_t stream) {
    const float* x   = (const float*)d_in[0];
    const int*   ei  = (const int*)d_in[1];
    const float* W1  = (const float*)d_in[2];
    const float* b1  = (const float*)d_in[3];
    const float* W1b = (const float*)d_in[4];
    const float* b1b = (const float*)d_in[5];
    const float* W2b = (const float*)d_in[6];
    const float* b2b = (const float*)d_in[7];
    const float* W2  = (const float*)d_in[8];
    const float* b2  = (const float*)d_in[9];
    float* out = (float*)d_out;

    const int F_IN = 500, H1 = 200, H2 = 100, H3 = 40;
    const int N = in_sizes[0] / F_IN;
    const int E = in_sizes[1] / 2;
    const int* src = ei;
    const int* dst = ei + E;

    // workspace carve-up
    size_t off = 0;
    auto alloc = [&](size_t bytes) -> void* {
        void* p = (char*)d_ws + off;
        off += (bytes + 255) & ~(size_t)255;
        return p;
    };
    int*   cnt       = (int*)  alloc((size_t)N * 4);
    int*   row_start = (int*)  alloc((size_t)(N + 1) * 4);
    int*   fill      = (int*)  alloc((size_t)N * 4);
    int*   partial   = (int*)  alloc(128 * 4);
    float* dinv      = (float*)alloc((size_t)N * 4);
    int*   csr_src   = (int*)  alloc((size_t)(E + N) * 4);
    float* csr_norm  = (float*)alloc((size_t)(E + N) * 4);
    float* bufA      = (float*)alloc((size_t)N * H1 * 4);
    float* bufB      = (float*)alloc((size_t)N * H1 * 4);

    int gN   = (N + 255) / 256;
    int gE   = (E + 255) / 256;
    int gEN  = (E + N + 255) / 256;
    int nb   = (N + 1023) / 1024;

    // --- CSR build ---
    k_init <<<gN, 256, 0, stream>>>(cnt, fill, N);
    k_count<<<gE, 256, 0, stream>>>(dst, cnt, E);
    k_dinv <<<gN, 256, 0, stream>>>(cnt, dinv, N);
    k_scan1<<<nb, 256, 0, stream>>>(cnt, row_start, partial, N);
    k_scan2<<<1, 128, 0, stream>>>(partial, nb);
    k_scan3<<<gN, 256, 0, stream>>>(row_start, partial, N, E + N);
    k_fill <<<gEN, 256, 0, stream>>>(src, dst, dinv, row_start, fill,
                                     csr_src, csr_norm, E, N);

    int wavesPerBlk = 4;                       // 256 threads
    int gAgg = (N + wavesPerBlk - 1) / wavesPerBlk;

    // --- layer 1: [N,500] @ [200,500]^T -> agg(relu) ---
    {
        dim3 grid((N + 63) / 64, (H1 + 63) / 64);
        gemm_nt<<<grid, 256, 0, stream>>>(x, W1, bufA, N, H1, F_IN);
        agg_wave<H1, true><<<gAgg, 256, 0, stream>>>(bufA, row_start, csr_src, csr_norm,
                                                     b1, bufB, N);
    }
    // --- layer 2: [N,200] @ [100,200]^T -> agg(relu) ---
    {
        dim3 grid((N + 63) / 64, (H2 + 63) / 64);
        gemm_nt<<<grid, 256, 0, stream>>>(bufB, W1b, bufA, N, H2, H1);
        agg_wave<H2, true><<<gAgg, 256, 0, stream>>>(bufA, row_start, csr_src, csr_norm,
                                                     b1b, bufB, N);
    }
    // --- layer 3: [N,100] @ [40,100]^T -> agg(relu) ---
    {
        dim3 grid((N + 63) / 64, (H3 + 63) / 64);
        gemm_nt<<<grid, 256, 0, stream>>>(bufB, W2b, bufA, N, H3, H2);
        agg_wave<H3, true><<<gAgg, 256, 0, stream>>>(bufA, row_start, csr_src, csr_norm,
                                                     b2b, bufB, N);
    }
    // --- layer 4: [N,40] @ [3,40]^T -> agg (no relu) -> d_out ---
    {
        gemm_small<<<(N + 255) / 256, 256, 0, stream>>>(bufB, W2, bufA, N, 3, H3);
        agg_tpf<3><<<(N * 3 + 255) / 256, 256, 0, stream>>>(bufA, row_start, csr_src,
                                                            csr_norm, b2, out, N);
    }
}

// Round 2
// 806.532 us; speedup vs baseline: 2.2296x; 2.2296x over previous
//
#include <hip/hip_runtime.h>

// ---------------------------------------------------------------------------
// GCN 4-layer inference. GEMMs via split-bf16 MFMA (hi/lo decomposition,
// 3x mfma_f32_16x16x32_bf16 -> ~fp32 accuracy at MFMA rate).
// Aggregation: CSR gather, float4-vectorized, norm recomputed from dinv.
// ---------------------------------------------------------------------------

#define DEV __device__ __forceinline__

typedef __attribute__((ext_vector_type(8))) short short8;
typedef __attribute__((ext_vector_type(4))) float f32x4;

DEV unsigned short f2bf(float x) {                 // fp32 -> bf16 RNE
    unsigned u = __builtin_bit_cast(unsigned, x);
    u += 0x7FFFu + ((u >> 16) & 1u);
    return (unsigned short)(u >> 16);
}
DEV float bf2f(unsigned short b) {
    return __builtin_bit_cast(float, (unsigned)b << 16);
}

// ---------------- CSR build ----------------

__global__ void k_init(int* __restrict__ cnt, int* __restrict__ fill, int n) {
    int i = blockIdx.x * 256 + threadIdx.x;
    if (i < n) { cnt[i] = 1; fill[i] = 0; }   // 1 = self-loop
}

__global__ void k_count(const int* __restrict__ dst, int* __restrict__ cnt, int E) {
    int e = blockIdx.x * 256 + threadIdx.x;
    if (e < E) atomicAdd(&cnt[dst[e]], 1);
}

__global__ void k_dinv(const int* __restrict__ cnt, float* __restrict__ dinv, int n) {
    int i = blockIdx.x * 256 + threadIdx.x;
    if (i < n) dinv[i] = rsqrtf((float)cnt[i]);
}

__global__ void k_scan1(const int* __restrict__ cnt, int* __restrict__ row_start,
                        int* __restrict__ partial, int n) {
    __shared__ int sdata[256];
    int base = blockIdx.x * 1024;
    int t = threadIdx.x;
    int v[4]; int sum = 0;
#pragma unroll
    for (int j = 0; j < 4; ++j) {
        int idx = base + t * 4 + j;
        v[j] = (idx < n) ? cnt[idx] : 0;
        sum += v[j];
    }
    sdata[t] = sum;
    __syncthreads();
    for (int off = 1; off < 256; off <<= 1) {
        int x = (t >= off) ? sdata[t - off] : 0;
        __syncthreads();
        sdata[t] += x;
        __syncthreads();
    }
    int excl = sdata[t] - sum;
#pragma unroll
    for (int j = 0; j < 4; ++j) {
        int idx = base + t * 4 + j;
        if (idx < n) row_start[idx] = excl;
        excl += v[j];
    }
    if (t == 255) partial[blockIdx.x] = sdata[255];
}

__global__ void k_scan2(int* __restrict__ partial, int nb) {
    __shared__ int s[128];
    int t = threadIdx.x;
    int v = (t < nb) ? partial[t] : 0;
    s[t] = v;
    __syncthreads();
    for (int off = 1; off < 128; off <<= 1) {
        int x = (t >= off) ? s[t - off] : 0;
        __syncthreads();
        s[t] += x;
        __syncthreads();
    }
    if (t < nb) partial[t] = s[t] - v;
}

__global__ void k_scan3(int* __restrict__ row_start, const int* __restrict__ partial,
                        int n, int total) {
    int i = blockIdx.x * 256 + threadIdx.x;
    if (i < n) row_start[i] += partial[i >> 10];
    if (i == 0) row_start[n] = total;
}

__global__ void k_fill(const int* __restrict__ src, const int* __restrict__ dst,
                       const int* __restrict__ row_start, int* __restrict__ fill,
                       int* __restrict__ csr_src, int E, int n) {
    int i = blockIdx.x * 256 + threadIdx.x;
    int total = E + n;
    if (i >= total) return;
    int s, d;
    if (i < E) { s = src[i]; d = dst[i]; }
    else       { s = d = i - E; }
    int pos = row_start[d] + atomicAdd(&fill[d], 1);
    csr_src[pos] = s;
}

// ---------------- weight decompose: W[N][K] fp32 -> padded bf16 hi/lo ----------------

__global__ void k_wdec(const float* __restrict__ W, int N, int K,
                       unsigned short* __restrict__ Wh, unsigned short* __restrict__ Wl,
                       int NPAD, int KPAD) {
    int i = blockIdx.x * 256 + threadIdx.x;
    if (i >= NPAD * KPAD) return;
    int r = i / KPAD, k = i - r * KPAD;
    float x = (r < N && k < K) ? W[r * K + k] : 0.f;
    unsigned short h = f2bf(x);
    unsigned short l = f2bf(x - bf2f(h));
    Wh[i] = h; Wl[i] = l;
}

// ---------------- MFMA GEMM: C[M][Nout] = A[M][K] @ W^T, split-bf16 ----------------
// Block: 512 threads = 8 waves; BM = 128 rows; each wave: 16 rows x NPAD cols.
// A read fp32 from global, converted to hi/lo in registers. W hi/lo staged in LDS
// with 80-byte row stride (bank-conflict ~2-way = free).

template <int NF>   // NPAD = NF*16
__global__ __launch_bounds__(512)
void gemm_mfma(const float* __restrict__ A, int lda, int M, int K,
               const unsigned short* __restrict__ Wh,
               const unsigned short* __restrict__ Wl, int ldw,
               float* __restrict__ C, int ldc, int Nout) {
    constexpr int NPAD = NF * 16;
    constexpr int RB = 80;                      // LDS bytes per 32-elem bf16 row
    __shared__ char lds[2 * NPAD * RB];
    char* ldsH = lds;
    char* ldsL = lds + NPAD * RB;

    const int tid  = threadIdx.x;
    const int wv   = tid >> 6;
    const int lane = tid & 63;
    const int lr   = lane & 15;                 // row within fragment
    const int kq   = lane >> 4;                 // k quarter (8 elems each)
    const int m0   = blockIdx.x * 128;

    int arow = m0 + wv * 16 + lr;
    if (arow >= M) arow = M - 1;                // clamp; stores are masked
    const float* Arow = A + (size_t)arow * lda;

    f32x4 acc[NF];
#pragma unroll
    for (int f = 0; f < NF; ++f) acc[f] = (f32x4){0.f, 0.f, 0.f, 0.f};

    const int nsteps = (K + 31) / 32;
    for (int s = 0; s < nsteps; ++s) {
        const int kb = s * 32;
        // ---- stage W hi/lo tiles (NPAD x 32 bf16 each) ----
        {
            const int CH = NPAD * 4;            // 16-byte chunks per buffer
            for (int c = tid; c < 2 * CH; c += 512) {
                int b    = (c >= CH);
                int cc   = c - b * CH;
                int r    = cc >> 2;
                int slot = cc & 3;
                const unsigned short* sp = (b ? Wl : Wh) + (size_t)r * ldw + kb + slot * 8;
                uint4 v = *(const uint4*)sp;
                *(uint4*)((b ? ldsL : ldsH) + r * RB + slot * 16) = v;
            }
        }
        __syncthreads();

        // ---- A fragment: 8 fp32 -> bf16 hi/lo ----
        float av[8];
        if (kb + 32 <= K) {
            const float* ap = Arow + kb + kq * 8;
            f32x4 v0 = *(const f32x4*)ap;
            f32x4 v1 = *(const f32x4*)(ap + 4);
#pragma unroll
            for (int i = 0; i < 4; ++i) { av[i] = v0[i]; av[4 + i] = v1[i]; }
        } else {
#pragma unroll
            for (int i = 0; i < 8; ++i) {
                int k = kb + kq * 8 + i;
                av[i] = (k < K) ? Arow[k] : 0.f;
            }
        }
        short8 ahi, alo;
#pragma unroll
        for (int i = 0; i < 8; ++i) {
            unsigned short h = f2bf(av[i]);
            ahi[i] = (short)h;
            alo[i] = (short)f2bf(av[i] - bf2f(h));
        }

        const int ro = lr * RB + kq * 16;
#pragma unroll
        for (int f = 0; f < NF; ++f) {
            short8 bh = *(const short8*)(ldsH + f * 16 * RB + ro);
            short8 bl = *(const short8*)(ldsL + f * 16 * RB + ro);
            acc[f] = __builtin_amdgcn_mfma_f32_16x16x32_bf16(ahi, bh, acc[f], 0, 0, 0);
            acc[f] = __builtin_amdgcn_mfma_f32_16x16x32_bf16(ahi, bl, acc[f], 0, 0, 0);
            acc[f] = __builtin_amdgcn_mfma_f32_16x16x32_bf16(alo, bh, acc[f], 0, 0, 0);
        }
        __syncthreads();
    }

    // ---- store: D row=(lane>>4)*4+j, col=lane&15 (m89-verified) ----
    const int rbase = m0 + wv * 16 + kq * 4;
#pragma unroll
    for (int f = 0; f < NF; ++f) {
        int col = f * 16 + lr;
#pragma unroll
        for (int j = 0; j < 4; ++j) {
            int row = rbase + j;
            if (row < M && col < Nout) C[(size_t)row * ldc + col] = acc[f][j];
        }
    }
}

// ---------------- aggregation: out[i] = sum_e dinv[s]*dinv[i]*h[s] + b ----------------
// float4 per lane; LPN = F/4 lanes per node; multiple nodes per wave for small F.

template <int F, bool RELU>
__global__ __launch_bounds__(256)
void agg_v4(const float* __restrict__ h, const int* __restrict__ row_start,
            const int* __restrict__ csr_src, const float* __restrict__ dinv,
            const float* __restrict__ bias, float* __restrict__ out, int n) {
    constexpr int LPN = F / 4;
    constexpr int NPW = 64 / LPN;
    int wave = blockIdx.x * 4 + (threadIdx.x >> 6);
    int lane = threadIdx.x & 63;
    int sub  = lane / LPN;
    int fi   = lane - sub * LPN;
    int node = wave * NPW + sub;
    if (sub >= NPW || node >= n) return;
    int f = fi * 4;

    f32x4 acc = {0.f, 0.f, 0.f, 0.f};
    int e0 = row_start[node], e1 = row_start[node + 1];
    float dn = dinv[node];
    for (int e = e0; e < e1; ++e) {
        int s = csr_src[e];
        float w = dinv[s] * dn;
        f32x4 v = *(const f32x4*)&h[(size_t)s * F + f];
        acc += v * w;
    }
    f32x4 b4 = *(const f32x4*)&bias[f];
    acc += b4;
    if (RELU) {
#pragma unroll
        for (int j = 0; j < 4; ++j) acc[j] = fmaxf(acc[j], 0.f);
    }
    *(f32x4*)&out[(size_t)node * F + f] = acc;
}

// ---------------- tiny layer-4 helpers (fp32) ----------------

__global__ void gemm_small(const float* __restrict__ A, const float* __restrict__ B,
                           float* __restrict__ C, int M, int K) {
    int m = blockIdx.x * 256 + threadIdx.x;
    if (m >= M) return;
    float a0 = 0.f, a1 = 0.f, a2 = 0.f;
    for (int k = 0; k < K; ++k) {
        float a = A[(size_t)m * K + k];
        a0 += a * B[0 * K + k];
        a1 += a * B[1 * K + k];
        a2 += a * B[2 * K + k];
    }
    C[(size_t)m * 3 + 0] = a0;
    C[(size_t)m * 3 + 1] = a1;
    C[(size_t)m * 3 + 2] = a2;
}

__global__ void agg_f3(const float* __restrict__ h, const int* __restrict__ row_start,
                       const int* __restrict__ csr_src, const float* __restrict__ dinv,
                       const float* __restrict__ bias, float* __restrict__ out, int n) {
    int i = blockIdx.x * 256 + threadIdx.x;
    if (i >= n * 3) return;
    int node = i / 3;
    int f = i - node * 3;
    float dn = dinv[node];
    float acc = 0.f;
    int e1 = row_start[node + 1];
    for (int e = row_start[node]; e < e1; ++e) {
        int s = csr_src[e];
        acc += h[(size_t)s * 3 + f] * dinv[s] * dn;
    }
    out[i] = acc + bias[f];
}

// ---------------------------------------------------------------------------

extern "C" void kernel_launch(void* const* d_in, const int* in_sizes, int n_in,
                              void* d_out, int out_size, void* d_ws, size_t ws_size,
                              hipStream_t stream) {
    const float* x   = (const float*)d_in[0];
    const int*   ei  = (const int*)d_in[1];
    const float* W1  = (const float*)d_in[2];
    const float* b1  = (const float*)d_in[3];
    const float* W1b = (const float*)d_in[4];
    const float* b1b = (const float*)d_in[5];
    const float* W2b = (const float*)d_in[6];
    const float* b2b = (const float*)d_in[7];
    const float* W2  = (const float*)d_in[8];
    const float* b2  = (const float*)d_in[9];
    float* out = (float*)d_out;

    const int F_IN = 500, H1 = 200, H2 = 100, H3 = 40;
    const int N = in_sizes[0] / F_IN;
    const int E = in_sizes[1] / 2;
    const int* src = ei;
    const int* dst = ei + E;

    size_t off = 0;
    auto alloc = [&](size_t bytes) -> void* {
        void* p = (char*)d_ws + off;
        off += (bytes + 255) & ~(size_t)255;
        return p;
    };
    int*   cnt       = (int*)  alloc((size_t)N * 4);
    int*   row_start = (int*)  alloc((size_t)(N + 1) * 4);
    int*   fill      = (int*)  alloc((size_t)N * 4);
    int*   partial   = (int*)  alloc(128 * 4);
    float* dinv      = (float*)alloc((size_t)N * 4);
    int*   csr_src   = (int*)  alloc((size_t)(E + N) * 4);
    unsigned short* wh1 = (unsigned short*)alloc(208 * 512 * 2);
    unsigned short* wl1 = (unsigned short*)alloc(208 * 512 * 2);
    unsigned short* wh2 = (unsigned short*)alloc(112 * 224 * 2);
    unsigned short* wl2 = (unsigned short*)alloc(112 * 224 * 2);
    unsigned short* wh3 = (unsigned short*)alloc(48 * 128 * 2);
    unsigned short* wl3 = (unsigned short*)alloc(48 * 128 * 2);
    float* bufA = (float*)alloc((size_t)N * H1 * 4);   // gemm outputs
    float* bufB = (float*)alloc((size_t)N * H1 * 4);   // agg outputs

    int gN  = (N + 255) / 256;
    int gE  = (E + 255) / 256;
    int gEN = (E + N + 255) / 256;
    int nb  = (N + 1023) / 1024;

    // --- CSR build ---
    k_init <<<gN, 256, 0, stream>>>(cnt, fill, N);
    k_count<<<gE, 256, 0, stream>>>(dst, cnt, E);
    k_dinv <<<gN, 256, 0, stream>>>(cnt, dinv, N);
    k_scan1<<<nb, 256, 0, stream>>>(cnt, row_start, partial, N);
    k_scan2<<<1, 128, 0, stream>>>(partial, nb);
    k_scan3<<<gN, 256, 0, stream>>>(row_start, partial, N, E + N);
    k_fill <<<gEN, 256, 0, stream>>>(src, dst, row_start, fill, csr_src, E, N);

    // --- weight decomposition ---
    k_wdec<<<(208 * 512 + 255) / 256, 256, 0, stream>>>(W1,  H1, F_IN, wh1, wl1, 208, 512);
    k_wdec<<<(112 * 224 + 255) / 256, 256, 0, stream>>>(W1b, H2, H1,   wh2, wl2, 112, 224);
    k_wdec<<<( 48 * 128 + 255) / 256, 256, 0, stream>>>(W2b, H3, H2,   wh3, wl3,  48, 128);

    const int gG = (N + 127) / 128;

    // --- layer 1 ---
    gemm_mfma<13><<<gG, 512, 0, stream>>>(x, F_IN, N, F_IN, wh1, wl1, 512, bufA, H1, H1);
    agg_v4<200, true><<<(N + 3) / 4, 256, 0, stream>>>(bufA, row_start, csr_src, dinv, b1, bufB, N);
    // --- layer 2 ---
    gemm_mfma<7><<<gG, 512, 0, stream>>>(bufB, H1, N, H1, wh2, wl2, 224, bufA, H2, H2);
    agg_v4<100, true><<<(N / 2 + 3) / 4, 256, 0, stream>>>(bufA, row_start, csr_src, dinv, b1b, bufB, N);
    // --- layer 3 ---
    gemm_mfma<3><<<gG, 512, 0, stream>>>(bufB, H2, N, H2, wh3, wl3, 128, bufA, H3, H3);
    {
        int waves = (N + 5) / 6, blocks = (waves + 3) / 4;
        agg_v4<40, true><<<blocks, 256, 0, stream>>>(bufA, row_start, csr_src, dinv, b2b, bufB, N);
    }
    // --- layer 4 ---
    gemm_small<<<(N + 255) / 256, 256, 0, stream>>>(bufB, W2, bufA, N, H3);
    agg_f3<<<(N * 3 + 255) / 256, 256, 0, stream>>>(bufA, row_start, csr_src, dinv, b2, out, N);
}

// Round 3
// 724.716 us; speedup vs baseline: 2.4813x; 1.1129x over previous
//
#include <hip/hip_runtime.h>

// ---------------------------------------------------------------------------
// GCN 4-layer inference.
//  - GEMMs: split-bf16 MFMA (hi/lo, 3x mfma_16x16x32_bf16 = ~fp32 accuracy).
//    Epilogue folds dinv[row] and stores the aggregation table as fp16.
//  - Aggregation: CSR gather of fp16 rows (half the bytes of r2), then
//    out = dinv[d]*sum + bias (+ReLU) in fp32.
// ---------------------------------------------------------------------------

#define DEV __device__ __forceinline__

typedef __attribute__((ext_vector_type(8))) short short8;
typedef __attribute__((ext_vector_type(4))) float f32x4;
typedef __attribute__((ext_vector_type(4))) _Float16 f16x4;

DEV unsigned short f2bf(float x) {                 // fp32 -> bf16 RNE
    unsigned u = __builtin_bit_cast(unsigned, x);
    u += 0x7FFFu + ((u >> 16) & 1u);
    return (unsigned short)(u >> 16);
}
DEV float bf2f(unsigned short b) {
    return __builtin_bit_cast(float, (unsigned)b << 16);
}

// ---------------- CSR build ----------------

__global__ void k_init(int* __restrict__ cnt, int* __restrict__ fill, int n) {
    int i = blockIdx.x * 256 + threadIdx.x;
    if (i < n) { cnt[i] = 1; fill[i] = 0; }   // 1 = self-loop
}

__global__ void k_count(const int* __restrict__ dst, int* __restrict__ cnt, int E) {
    int e = blockIdx.x * 256 + threadIdx.x;
    if (e < E) atomicAdd(&cnt[dst[e]], 1);
}

// scan 1024 per block; also emits dinv = rsqrt(cnt)
__global__ void k_scan1(const int* __restrict__ cnt, int* __restrict__ row_start,
                        int* __restrict__ partial, float* __restrict__ dinv, int n) {
    __shared__ int sdata[256];
    int base = blockIdx.x * 1024;
    int t = threadIdx.x;
    int v[4]; int sum = 0;
#pragma unroll
    for (int j = 0; j < 4; ++j) {
        int idx = base + t * 4 + j;
        v[j] = (idx < n) ? cnt[idx] : 0;
        if (idx < n) dinv[idx] = rsqrtf((float)v[j]);
        sum += v[j];
    }
    sdata[t] = sum;
    __syncthreads();
    for (int off = 1; off < 256; off <<= 1) {
        int x = (t >= off) ? sdata[t - off] : 0;
        __syncthreads();
        sdata[t] += x;
        __syncthreads();
    }
    int excl = sdata[t] - sum;
#pragma unroll
    for (int j = 0; j < 4; ++j) {
        int idx = base + t * 4 + j;
        if (idx < n) row_start[idx] = excl;
        excl += v[j];
    }
    if (t == 255) partial[blockIdx.x] = sdata[255];
}

__global__ void k_scan2(int* __restrict__ partial, int nb) {
    __shared__ int s[128];
    int t = threadIdx.x;
    int v = (t < nb) ? partial[t] : 0;
    s[t] = v;
    __syncthreads();
    for (int off = 1; off < 128; off <<= 1) {
        int x = (t >= off) ? s[t - off] : 0;
        __syncthreads();
        s[t] += x;
        __syncthreads();
    }
    if (t < nb) partial[t] = s[t] - v;
}

__global__ void k_scan3(int* __restrict__ row_start, const int* __restrict__ partial,
                        int n, int total) {
    int i = blockIdx.x * 256 + threadIdx.x;
    if (i < n) row_start[i] += partial[i >> 10];
    if (i == 0) row_start[n] = total;
}

__global__ void k_fill(const int* __restrict__ src, const int* __restrict__ dst,
                       const int* __restrict__ row_start, int* __restrict__ fill,
                       int* __restrict__ csr_src, int E, int n) {
    int i = blockIdx.x * 256 + threadIdx.x;
    int total = E + n;
    if (i >= total) return;
    int s, d;
    if (i < E) { s = src[i]; d = dst[i]; }
    else       { s = d = i - E; }
    int pos = row_start[d] + atomicAdd(&fill[d], 1);
    csr_src[pos] = s;
}

// ---------------- weight decompose: W[N][K] fp32 -> padded bf16 hi/lo ----------------

__global__ void k_wdec(const float* __restrict__ W, int N, int K,
                       unsigned short* __restrict__ Wh, unsigned short* __restrict__ Wl,
                       int NPAD, int KPAD) {
    int i = blockIdx.x * 256 + threadIdx.x;
    if (i >= NPAD * KPAD) return;
    int r = i / KPAD, k = i - r * KPAD;
    float x = (r < N && k < K) ? W[r * K + k] : 0.f;
    unsigned short h = f2bf(x);
    unsigned short l = f2bf(x - bf2f(h));
    Wh[i] = h; Wl[i] = l;
}

// ---------------- MFMA GEMM: H16[m][c] = (A[m][:] . W[c][:]) * dinv[m], fp16 ----------
// 512 thr = 8 waves; BM = 128 rows; each wave 16 rows x NPAD cols.
// A fp32 from global -> bf16 hi/lo in registers. W hi/lo staged in LDS (80-B rows).

template <int NF>   // NPAD = NF*16
__global__ __launch_bounds__(512)
void gemm_mfma(const float* __restrict__ A, int lda, int M, int K,
               const unsigned short* __restrict__ Wh,
               const unsigned short* __restrict__ Wl, int ldw,
               const float* __restrict__ dinv,
               _Float16* __restrict__ H16, int ldh, int Nout) {
    constexpr int NPAD = NF * 16;
    constexpr int RB = 80;
    __shared__ char lds[2 * NPAD * RB];
    char* ldsH = lds;
    char* ldsL = lds + NPAD * RB;

    const int tid  = threadIdx.x;
    const int wv   = tid >> 6;
    const int lane = tid & 63;
    const int lr   = lane & 15;
    const int kq   = lane >> 4;
    const int m0   = blockIdx.x * 128;

    int arow = m0 + wv * 16 + lr;
    if (arow >= M) arow = M - 1;
    const float* Arow = A + (size_t)arow * lda;

    f32x4 acc[NF];
#pragma unroll
    for (int f = 0; f < NF; ++f) acc[f] = (f32x4){0.f, 0.f, 0.f, 0.f};

    const int nsteps = (K + 31) / 32;
    for (int s = 0; s < nsteps; ++s) {
        const int kb = s * 32;
        {
            const int CH = NPAD * 4;
            for (int c = tid; c < 2 * CH; c += 512) {
                int b    = (c >= CH);
                int cc   = c - b * CH;
                int r    = cc >> 2;
                int slot = cc & 3;
                const unsigned short* sp = (b ? Wl : Wh) + (size_t)r * ldw + kb + slot * 8;
                uint4 v = *(const uint4*)sp;
                *(uint4*)((b ? ldsL : ldsH) + r * RB + slot * 16) = v;
            }
        }
        __syncthreads();

        float av[8];
        if (kb + 32 <= K) {
            const float* ap = Arow + kb + kq * 8;
            f32x4 v0 = *(const f32x4*)ap;
            f32x4 v1 = *(const f32x4*)(ap + 4);
#pragma unroll
            for (int i = 0; i < 4; ++i) { av[i] = v0[i]; av[4 + i] = v1[i]; }
        } else {
#pragma unroll
            for (int i = 0; i < 8; ++i) {
                int k = kb + kq * 8 + i;
                av[i] = (k < K) ? Arow[k] : 0.f;
            }
        }
        short8 ahi, alo;
#pragma unroll
        for (int i = 0; i < 8; ++i) {
            unsigned short h = f2bf(av[i]);
            ahi[i] = (short)h;
            alo[i] = (short)f2bf(av[i] - bf2f(h));
        }

        const int ro = lr * RB + kq * 16;
#pragma unroll
        for (int f = 0; f < NF; ++f) {
            short8 bh = *(const short8*)(ldsH + f * 16 * RB + ro);
            short8 bl = *(const short8*)(ldsL + f * 16 * RB + ro);
            acc[f] = __builtin_amdgcn_mfma_f32_16x16x32_bf16(ahi, bh, acc[f], 0, 0, 0);
            acc[f] = __builtin_amdgcn_mfma_f32_16x16x32_bf16(ahi, bl, acc[f], 0, 0, 0);
            acc[f] = __builtin_amdgcn_mfma_f32_16x16x32_bf16(alo, bh, acc[f], 0, 0, 0);
        }
        __syncthreads();
    }

    // store: D row=(lane>>4)*4+j, col=lane&15; scale by dinv[row], cast fp16
    const int rbase = m0 + wv * 16 + kq * 4;
    float dv[4];
#pragma unroll
    for (int j = 0; j < 4; ++j) {
        int row = rbase + j;
        dv[j] = (row < M) ? dinv[row] : 0.f;
    }
#pragma unroll
    for (int f = 0; f < NF; ++f) {
        int col = f * 16 + lr;
        if (col >= Nout) continue;
#pragma unroll
        for (int j = 0; j < 4; ++j) {
            int row = rbase + j;
            if (row < M) H16[(size_t)row * ldh + col] = (_Float16)(acc[f][j] * dv[j]);
        }
    }
}

// ---------------- aggregation: out = dinv[d] * sum_e h16[src_e] + b ----------------
// fp16 gather, 4 features (8 B) per lane.

template <int F, bool RELU>
__global__ __launch_bounds__(256)
void agg_f16(const _Float16* __restrict__ h, const int* __restrict__ row_start,
             const int* __restrict__ csr_src, const float* __restrict__ dinv,
             const float* __restrict__ bias, float* __restrict__ out, int n) {
    constexpr int LPN = F / 4;
    constexpr int NPW = 64 / LPN;
    int wave = blockIdx.x * 4 + (threadIdx.x >> 6);
    int lane = threadIdx.x & 63;
    int sub  = lane / LPN;
    int fi   = lane - sub * LPN;
    int node = wave * NPW + sub;
    if (sub >= NPW || node >= n) return;
    int f = fi * 4;

    f32x4 acc = {0.f, 0.f, 0.f, 0.f};
    int e0 = row_start[node], e1 = row_start[node + 1];
    for (int e = e0; e < e1; ++e) {
        int s = csr_src[e];
        f16x4 v = *(const f16x4*)&h[(size_t)s * F + f];
        acc += __builtin_convertvector(v, f32x4);
    }
    float dn = dinv[node];
    f32x4 b4 = *(const f32x4*)&bias[f];
    acc = acc * dn + b4;
    if (RELU) {
#pragma unroll
        for (int j = 0; j < 4; ++j) acc[j] = fmaxf(acc[j], 0.f);
    }
    *(f32x4*)&out[(size_t)node * F + f] = acc;
}

// ---------------- tiny layer-4 helpers (fp32) ----------------

__global__ void gemm_small(const float* __restrict__ A, const float* __restrict__ B,
                           const float* __restrict__ dinv, float* __restrict__ C,
                           int M, int K) {
    int m = blockIdx.x * 256 + threadIdx.x;
    if (m >= M) return;
    float a0 = 0.f, a1 = 0.f, a2 = 0.f;
    for (int k = 0; k < K; ++k) {
        float a = A[(size_t)m * K + k];
        a0 += a * B[0 * K + k];
        a1 += a * B[1 * K + k];
        a2 += a * B[2 * K + k];
    }
    float dv = dinv[m];
    C[(size_t)m * 3 + 0] = a0 * dv;
    C[(size_t)m * 3 + 1] = a1 * dv;
    C[(size_t)m * 3 + 2] = a2 * dv;
}

__global__ void agg_f3(const float* __restrict__ h, const int* __restrict__ row_start,
                       const int* __restrict__ csr_src, const float* __restrict__ dinv,
                       const float* __restrict__ bias, float* __restrict__ out, int n) {
    int i = blockIdx.x * 256 + threadIdx.x;
    if (i >= n * 3) return;
    int node = i / 3;
    int f = i - node * 3;
    float acc = 0.f;
    int e1 = row_start[node + 1];
    for (int e = row_start[node]; e < e1; ++e) {
        int s = csr_src[e];
        acc += h[(size_t)s * 3 + f];
    }
    out[i] = acc * dinv[node] + bias[f];
}

// ---------------------------------------------------------------------------

extern "C" void kernel_launch(void* const* d_in, const int* in_sizes, int n_in,
                              void* d_out, int out_size, void* d_ws, size_t ws_size,
                              hipStream_t stream) {
    const float* x   = (const float*)d_in[0];
    const int*   ei  = (const int*)d_in[1];
    const float* W1  = (const float*)d_in[2];
    const float* b1  = (const float*)d_in[3];
    const float* W1b = (const float*)d_in[4];
    const float* b1b = (const float*)d_in[5];
    const float* W2b = (const float*)d_in[6];
    const float* b2b = (const float*)d_in[7];
    const float* W2  = (const float*)d_in[8];
    const float* b2  = (const float*)d_in[9];
    float* out = (float*)d_out;

    const int F_IN = 500, H1 = 200, H2 = 100, H3 = 40;
    const int N = in_sizes[0] / F_IN;
    const int E = in_sizes[1] / 2;
    const int* src = ei;
    const int* dst = ei + E;

    size_t off = 0;
    auto alloc = [&](size_t bytes) -> void* {
        void* p = (char*)d_ws + off;
        off += (bytes + 255) & ~(size_t)255;
        return p;
    };
    int*   cnt       = (int*)  alloc((size_t)N * 4);
    int*   row_start = (int*)  alloc((size_t)(N + 1) * 4);
    int*   fill      = (int*)  alloc((size_t)N * 4);
    int*   partial   = (int*)  alloc(128 * 4);
    float* dinv      = (float*)alloc((size_t)N * 4);
    int*   csr_src   = (int*)  alloc((size_t)(E + N) * 4);
    unsigned short* wh1 = (unsigned short*)alloc(208 * 512 * 2);
    unsigned short* wl1 = (unsigned short*)alloc(208 * 512 * 2);
    unsigned short* wh2 = (unsigned short*)alloc(112 * 224 * 2);
    unsigned short* wl2 = (unsigned short*)alloc(112 * 224 * 2);
    unsigned short* wh3 = (unsigned short*)alloc(48 * 128 * 2);
    unsigned short* wl3 = (unsigned short*)alloc(48 * 128 * 2);
    _Float16* h16  = (_Float16*)alloc((size_t)N * H1 * 2);  // gemm outputs (scaled fp16)
    float*    bufB = (float*)   alloc((size_t)N * H1 * 4);  // agg outputs (fp32)
    float*    bufC = (float*)   alloc((size_t)N * 3 * 4);   // layer-4 gemm out

    int gN  = (N + 255) / 256;
    int gE  = (E + 255) / 256;
    int gEN = (E + N + 255) / 256;
    int nb  = (N + 1023) / 1024;

    // --- CSR build ---
    k_init <<<gN, 256, 0, stream>>>(cnt, fill, N);
    k_count<<<gE, 256, 0, stream>>>(dst, cnt, E);
    k_scan1<<<nb, 256, 0, stream>>>(cnt, row_start, partial, dinv, N);
    k_scan2<<<1, 128, 0, stream>>>(partial, nb);
    k_scan3<<<gN, 256, 0, stream>>>(row_start, partial, N, E + N);
    k_fill <<<gEN, 256, 0, stream>>>(src, dst, row_start, fill, csr_src, E, N);

    // --- weight decomposition ---
    k_wdec<<<(208 * 512 + 255) / 256, 256, 0, stream>>>(W1,  H1, F_IN, wh1, wl1, 208, 512);
    k_wdec<<<(112 * 224 + 255) / 256, 256, 0, stream>>>(W1b, H2, H1,   wh2, wl2, 112, 224);
    k_wdec<<<( 48 * 128 + 255) / 256, 256, 0, stream>>>(W2b, H3, H2,   wh3, wl3,  48, 128);

    const int gG = (N + 127) / 128;

    // --- layer 1 ---
    gemm_mfma<13><<<gG, 512, 0, stream>>>(x, F_IN, N, F_IN, wh1, wl1, 512, dinv, h16, H1, H1);
    agg_f16<200, true><<<(N + 3) / 4, 256, 0, stream>>>(h16, row_start, csr_src, dinv, b1, bufB, N);
    // --- layer 2 ---
    gemm_mfma<7><<<gG, 512, 0, stream>>>(bufB, H1, N, H1, wh2, wl2, 224, dinv, h16, H2, H2);
    agg_f16<100, true><<<(N / 2 + 3) / 4, 256, 0, stream>>>(h16, row_start, csr_src, dinv, b1b, bufB, N);
    // --- layer 3 ---
    gemm_mfma<3><<<gG, 512, 0, stream>>>(bufB, H2, N, H2, wh3, wl3, 128, dinv, h16, H3, H3);
    {
        int waves = (N + 5) / 6, blocks = (waves + 3) / 4;
        agg_f16<40, true><<<blocks, 256, 0, stream>>>(h16, row_start, csr_src, dinv, b2b, bufB, N);
    }
    // --- layer 4 ---
    gemm_small<<<(N + 255) / 256, 256, 0, stream>>>(bufB, W2, dinv, bufC, N, H3);
    agg_f3<<<(N * 3 + 255) / 256, 256, 0, stream>>>(bufC, row_start, csr_src, dinv, b2, out, N);
}

// Round 4
// 598.219 us; speedup vs baseline: 3.0060x; 1.2115x over previous
//
#include <hip/hip_runtime.h>

// ---------------------------------------------------------------------------
// GCN 4-layer inference.
//  - GEMMs: split-bf16 MFMA (hi/lo, 3x mfma_16x16x32_bf16 = ~fp32 accuracy).
//    Epilogue folds dinv[row], stores aggregation table fp16.
//  - Activations between layers are fp16 (exact under split-bf16 re-read).
//  - Aggregation: CSR gather of fp16 rows, 4-deep software-pipelined for MLP.
// ---------------------------------------------------------------------------

#define DEV __device__ __forceinline__

typedef __attribute__((ext_vector_type(8))) short short8;
typedef __attribute__((ext_vector_type(4))) float f32x4;
typedef __attribute__((ext_vector_type(4))) _Float16 f16x4;

DEV unsigned short f2bf(float x) {                 // fp32 -> bf16 RNE
    unsigned u = __builtin_bit_cast(unsigned, x);
    u += 0x7FFFu + ((u >> 16) & 1u);
    return (unsigned short)(u >> 16);
}
DEV float bf2f(unsigned short b) {
    return __builtin_bit_cast(float, (unsigned)b << 16);
}

// ---------------- CSR build ----------------

__global__ void k_init(int* __restrict__ cnt, int* __restrict__ fill, int n) {
    int i = blockIdx.x * 256 + threadIdx.x;
    if (i < n) { cnt[i] = 1; fill[i] = 0; }   // 1 = self-loop
}

__global__ void k_count(const int* __restrict__ dst, int* __restrict__ cnt, int E) {
    int e = blockIdx.x * 256 + threadIdx.x;
    if (e < E) atomicAdd(&cnt[dst[e]], 1);
}

__global__ void k_scan1(const int* __restrict__ cnt, int* __restrict__ row_start,
                        int* __restrict__ partial, float* __restrict__ dinv, int n) {
    __shared__ int sdata[256];
    int base = blockIdx.x * 1024;
    int t = threadIdx.x;
    int v[4]; int sum = 0;
#pragma unroll
    for (int j = 0; j < 4; ++j) {
        int idx = base + t * 4 + j;
        v[j] = (idx < n) ? cnt[idx] : 0;
        if (idx < n) dinv[idx] = rsqrtf((float)v[j]);
        sum += v[j];
    }
    sdata[t] = sum;
    __syncthreads();
    for (int off = 1; off < 256; off <<= 1) {
        int x = (t >= off) ? sdata[t - off] : 0;
        __syncthreads();
        sdata[t] += x;
        __syncthreads();
    }
    int excl = sdata[t] - sum;
#pragma unroll
    for (int j = 0; j < 4; ++j) {
        int idx = base + t * 4 + j;
        if (idx < n) row_start[idx] = excl;
        excl += v[j];
    }
    if (t == 255) partial[blockIdx.x] = sdata[255];
}

__global__ void k_scan2(int* __restrict__ partial, int nb) {
    __shared__ int s[128];
    int t = threadIdx.x;
    int v = (t < nb) ? partial[t] : 0;
    s[t] = v;
    __syncthreads();
    for (int off = 1; off < 128; off <<= 1) {
        int x = (t >= off) ? s[t - off] : 0;
        __syncthreads();
        s[t] += x;
        __syncthreads();
    }
    if (t < nb) partial[t] = s[t] - v;
}

__global__ void k_scan3(int* __restrict__ row_start, const int* __restrict__ partial,
                        int n, int total) {
    int i = blockIdx.x * 256 + threadIdx.x;
    if (i < n) row_start[i] += partial[i >> 10];
    if (i == 0) row_start[n] = total;
}

__global__ void k_fill(const int* __restrict__ src, const int* __restrict__ dst,
                       const int* __restrict__ row_start, int* __restrict__ fill,
                       int* __restrict__ csr_src, int E, int n) {
    int i = blockIdx.x * 256 + threadIdx.x;
    int total = E + n;
    if (i >= total) return;
    int s, d;
    if (i < E) { s = src[i]; d = dst[i]; }
    else       { s = d = i - E; }
    int pos = row_start[d] + atomicAdd(&fill[d], 1);
    csr_src[pos] = s;
}

// ---------------- weight decompose: W[N][K] fp32 -> padded bf16 hi/lo ----------------

__global__ void k_wdec(const float* __restrict__ W, int N, int K,
                       unsigned short* __restrict__ Wh, unsigned short* __restrict__ Wl,
                       int NPAD, int KPAD) {
    int i = blockIdx.x * 256 + threadIdx.x;
    if (i >= NPAD * KPAD) return;
    int r = i / KPAD, k = i - r * KPAD;
    float x = (r < N && k < K) ? W[r * K + k] : 0.f;
    unsigned short h = f2bf(x);
    unsigned short l = f2bf(x - bf2f(h));
    Wh[i] = h; Wl[i] = l;
}

// ---------------- MFMA GEMM: H16[m][c] = (A[m][:] . W[c][:]) * dinv[m], fp16 ----------
// 512 thr = 8 waves; BM = 128 rows; wave = 16 rows x NPAD cols.
// A (fp32 or fp16) -> bf16 hi/lo in registers. W hi/lo staged in LDS (80-B rows).

template <int NF, typename AT>   // NPAD = NF*16
__global__ __launch_bounds__(512)
void gemm_mfma(const AT* __restrict__ A, int lda, int M, int K,
               const unsigned short* __restrict__ Wh,
               const unsigned short* __restrict__ Wl, int ldw,
               const float* __restrict__ dinv,
               _Float16* __restrict__ H16, int ldh, int Nout) {
    constexpr int NPAD = NF * 16;
    constexpr int RB = 80;
    __shared__ char lds[2 * NPAD * RB];
    char* ldsH = lds;
    char* ldsL = lds + NPAD * RB;

    const int tid  = threadIdx.x;
    const int wv   = tid >> 6;
    const int lane = tid & 63;
    const int lr   = lane & 15;
    const int kq   = lane >> 4;
    const int m0   = blockIdx.x * 128;

    int arow = m0 + wv * 16 + lr;
    if (arow >= M) arow = M - 1;
    const AT* Arow = A + (size_t)arow * lda;

    f32x4 acc[NF];
#pragma unroll
    for (int f = 0; f < NF; ++f) acc[f] = (f32x4){0.f, 0.f, 0.f, 0.f};

    const int nsteps = (K + 31) / 32;
    for (int s = 0; s < nsteps; ++s) {
        const int kb = s * 32;
        {
            const int CH = NPAD * 4;
            for (int c = tid; c < 2 * CH; c += 512) {
                int b    = (c >= CH);
                int cc   = c - b * CH;
                int r    = cc >> 2;
                int slot = cc & 3;
                const unsigned short* sp = (b ? Wl : Wh) + (size_t)r * ldw + kb + slot * 8;
                uint4 v = *(const uint4*)sp;
                *(uint4*)((b ? ldsL : ldsH) + r * RB + slot * 16) = v;
            }
        }
        __syncthreads();

        float av[8];
        if (kb + 32 <= K) {
            if constexpr (sizeof(AT) == 4) {
                const float* ap = (const float*)Arow + kb + kq * 8;
                f32x4 v0 = *(const f32x4*)ap;
                f32x4 v1 = *(const f32x4*)(ap + 4);
#pragma unroll
                for (int i = 0; i < 4; ++i) { av[i] = v0[i]; av[4 + i] = v1[i]; }
            } else {
                const _Float16* ap = (const _Float16*)Arow + kb + kq * 8;
                f16x4 v0 = *(const f16x4*)ap;
                f16x4 v1 = *(const f16x4*)(ap + 4);
#pragma unroll
                for (int i = 0; i < 4; ++i) { av[i] = (float)v0[i]; av[4 + i] = (float)v1[i]; }
            }
        } else {
#pragma unroll
            for (int i = 0; i < 8; ++i) {
                int k = kb + kq * 8 + i;
                av[i] = (k < K) ? (float)Arow[k] : 0.f;
            }
        }
        short8 ahi, alo;
#pragma unroll
        for (int i = 0; i < 8; ++i) {
            unsigned short h = f2bf(av[i]);
            ahi[i] = (short)h;
            alo[i] = (short)f2bf(av[i] - bf2f(h));
        }

        const int ro = lr * RB + kq * 16;
#pragma unroll
        for (int f = 0; f < NF; ++f) {
            short8 bh = *(const short8*)(ldsH + f * 16 * RB + ro);
            short8 bl = *(const short8*)(ldsL + f * 16 * RB + ro);
            acc[f] = __builtin_amdgcn_mfma_f32_16x16x32_bf16(ahi, bh, acc[f], 0, 0, 0);
            acc[f] = __builtin_amdgcn_mfma_f32_16x16x32_bf16(ahi, bl, acc[f], 0, 0, 0);
            acc[f] = __builtin_amdgcn_mfma_f32_16x16x32_bf16(alo, bh, acc[f], 0, 0, 0);
        }
        __syncthreads();
    }

    const int rbase = m0 + wv * 16 + kq * 4;
    float dv[4];
#pragma unroll
    for (int j = 0; j < 4; ++j) {
        int row = rbase + j;
        dv[j] = (row < M) ? dinv[row] : 0.f;
    }
#pragma unroll
    for (int f = 0; f < NF; ++f) {
        int col = f * 16 + lr;
        if (col >= Nout) continue;
#pragma unroll
        for (int j = 0; j < 4; ++j) {
            int row = rbase + j;
            if (row < M) H16[(size_t)row * ldh + col] = (_Float16)(acc[f][j] * dv[j]);
        }
    }
}

// ---------------- aggregation: out = dinv[d] * sum_e h16[src_e] + b -----------------
// fp16 gather, 4 features (8 B) per lane; edge loop 4-deep software-pipelined.

template <int F, bool RELU>
__global__ __launch_bounds__(256)
void agg_f16(const _Float16* __restrict__ h, const int* __restrict__ row_start,
             const int* __restrict__ csr_src, const float* __restrict__ dinv,
             const float* __restrict__ bias, _Float16* __restrict__ out, int n) {
    constexpr int LPN = F / 4;
    constexpr int NPW = 64 / LPN;
    int wave = blockIdx.x * 4 + (threadIdx.x >> 6);
    int lane = threadIdx.x & 63;
    int sub  = lane / LPN;
    int fi   = lane - sub * LPN;
    int node = wave * NPW + sub;
    if (sub >= NPW || node >= n) return;
    int f = fi * 4;
    const _Float16* hf = h + f;

    f32x4 acc = {0.f, 0.f, 0.f, 0.f};
    int e0 = row_start[node], e1 = row_start[node + 1];
    int e = e0;
    for (; e + 4 <= e1; e += 4) {
        int s0 = csr_src[e + 0];
        int s1 = csr_src[e + 1];
        int s2 = csr_src[e + 2];
        int s3 = csr_src[e + 3];
        f16x4 v0 = *(const f16x4*)&hf[(size_t)s0 * F];
        f16x4 v1 = *(const f16x4*)&hf[(size_t)s1 * F];
        f16x4 v2 = *(const f16x4*)&hf[(size_t)s2 * F];
        f16x4 v3 = *(const f16x4*)&hf[(size_t)s3 * F];
        acc += __builtin_convertvector(v0, f32x4);
        acc += __builtin_convertvector(v1, f32x4);
        acc += __builtin_convertvector(v2, f32x4);
        acc += __builtin_convertvector(v3, f32x4);
    }
    for (; e < e1; ++e) {
        int s = csr_src[e];
        f16x4 v = *(const f16x4*)&hf[(size_t)s * F];
        acc += __builtin_convertvector(v, f32x4);
    }
    float dn = dinv[node];
    f32x4 b4 = *(const f32x4*)&bias[f];
    acc = acc * dn + b4;
    if (RELU) {
#pragma unroll
        for (int j = 0; j < 4; ++j) acc[j] = fmaxf(acc[j], 0.f);
    }
    f16x4 o;
#pragma unroll
    for (int j = 0; j < 4; ++j) o[j] = (_Float16)acc[j];
    *(f16x4*)&out[(size_t)node * F + f] = o;
}

// ---------------- tiny layer-4 helpers ----------------

__global__ void gemm_small(const _Float16* __restrict__ A, const float* __restrict__ B,
                           const float* __restrict__ dinv, float* __restrict__ C,
                           int M, int K) {
    int m = blockIdx.x * 256 + threadIdx.x;
    if (m >= M) return;
    float a0 = 0.f, a1 = 0.f, a2 = 0.f;
    for (int k = 0; k < K; ++k) {
        float a = (float)A[(size_t)m * K + k];
        a0 += a * B[0 * K + k];
        a1 += a * B[1 * K + k];
        a2 += a * B[2 * K + k];
    }
    float dv = dinv[m];
    C[(size_t)m * 3 + 0] = a0 * dv;
    C[(size_t)m * 3 + 1] = a1 * dv;
    C[(size_t)m * 3 + 2] = a2 * dv;
}

__global__ void agg_f3(const float* __restrict__ h, const int* __restrict__ row_start,
                       const int* __restrict__ csr_src, const float* __restrict__ dinv,
                       const float* __restrict__ bias, float* __restrict__ out, int n) {
    int i = blockIdx.x * 256 + threadIdx.x;
    if (i >= n * 3) return;
    int node = i / 3;
    int f = i - node * 3;
    float acc = 0.f;
    int e1 = row_start[node + 1];
    for (int e = row_start[node]; e < e1; ++e) {
        int s = csr_src[e];
        acc += h[(size_t)s * 3 + f];
    }
    out[i] = acc * dinv[node] + bias[f];
}

// ---------------------------------------------------------------------------

extern "C" void kernel_launch(void* const* d_in, const int* in_sizes, int n_in,
                              void* d_out, int out_size, void* d_ws, size_t ws_size,
                              hipStream_t stream) {
    const float* x   = (const float*)d_in[0];
    const int*   ei  = (const int*)d_in[1];
    const float* W1  = (const float*)d_in[2];
    const float* b1  = (const float*)d_in[3];
    const float* W1b = (const float*)d_in[4];
    const float* b1b = (const float*)d_in[5];
    const float* W2b = (const float*)d_in[6];
    const float* b2b = (const float*)d_in[7];
    const float* W2  = (const float*)d_in[8];
    const float* b2  = (const float*)d_in[9];
    float* out = (float*)d_out;

    const int F_IN = 500, H1 = 200, H2 = 100, H3 = 40;
    const int N = in_sizes[0] / F_IN;
    const int E = in_sizes[1] / 2;
    const int* src = ei;
    const int* dst = ei + E;

    size_t off = 0;
    auto alloc = [&](size_t bytes) -> void* {
        void* p = (char*)d_ws + off;
        off += (bytes + 255) & ~(size_t)255;
        return p;
    };
    int*   cnt       = (int*)  alloc((size_t)N * 4);
    int*   row_start = (int*)  alloc((size_t)(N + 1) * 4);
    int*   fill      = (int*)  alloc((size_t)N * 4);
    int*   partial   = (int*)  alloc(128 * 4);
    float* dinv      = (float*)alloc((size_t)N * 4);
    int*   csr_src   = (int*)  alloc((size_t)(E + N) * 4);
    unsigned short* wh1 = (unsigned short*)alloc(208 * 512 * 2);
    unsigned short* wl1 = (unsigned short*)alloc(208 * 512 * 2);
    unsigned short* wh2 = (unsigned short*)alloc(112 * 224 * 2);
    unsigned short* wl2 = (unsigned short*)alloc(112 * 224 * 2);
    unsigned short* wh3 = (unsigned short*)alloc(48 * 128 * 2);
    unsigned short* wl3 = (unsigned short*)alloc(48 * 128 * 2);
    _Float16* h16   = (_Float16*)alloc((size_t)N * H1 * 2);  // gemm outputs (scaled fp16)
    _Float16* act16 = (_Float16*)alloc((size_t)N * H1 * 2);  // agg outputs (fp16)
    float*    bufC  = (float*)   alloc((size_t)N * 3 * 4);   // layer-4 gemm out

    int gN  = (N + 255) / 256;
    int gE  = (E + 255) / 256;
    int gEN = (E + N + 255) / 256;
    int nb  = (N + 1023) / 1024;

    // --- CSR build ---
    k_init <<<gN, 256, 0, stream>>>(cnt, fill, N);
    k_count<<<gE, 256, 0, stream>>>(dst, cnt, E);
    k_scan1<<<nb, 256, 0, stream>>>(cnt, row_start, partial, dinv, N);
    k_scan2<<<1, 128, 0, stream>>>(partial, nb);
    k_scan3<<<gN, 256, 0, stream>>>(row_start, partial, N, E + N);
    k_fill <<<gEN, 256, 0, stream>>>(src, dst, row_start, fill, csr_src, E, N);

    // --- weight decomposition ---
    k_wdec<<<(208 * 512 + 255) / 256, 256, 0, stream>>>(W1,  H1, F_IN, wh1, wl1, 208, 512);
    k_wdec<<<(112 * 224 + 255) / 256, 256, 0, stream>>>(W1b, H2, H1,   wh2, wl2, 112, 224);
    k_wdec<<<( 48 * 128 + 255) / 256, 256, 0, stream>>>(W2b, H3, H2,   wh3, wl3,  48, 128);

    const int gG = (N + 127) / 128;

    // --- layer 1 ---
    gemm_mfma<13, float><<<gG, 512, 0, stream>>>(x, F_IN, N, F_IN, wh1, wl1, 512,
                                                 dinv, h16, H1, H1);
    agg_f16<200, true><<<(N + 3) / 4, 256, 0, stream>>>(h16, row_start, csr_src, dinv,
                                                        b1, act16, N);
    // --- layer 2 ---
    gemm_mfma<7, _Float16><<<gG, 512, 0, stream>>>(act16, H1, N, H1, wh2, wl2, 224,
                                                   dinv, h16, H2, H2);
    agg_f16<100, true><<<(N / 2 + 3) / 4, 256, 0, stream>>>(h16, row_start, csr_src, dinv,
                                                            b1b, act16, N);
    // --- layer 3 ---
    gemm_mfma<3, _Float16><<<gG, 512, 0, stream>>>(act16, H2, N, H2, wh3, wl3, 128,
                                                   dinv, h16, H3, H3);
    {
        int waves = (N + 5) / 6, blocks = (waves + 3) / 4;
        agg_f16<40, true><<<blocks, 256, 0, stream>>>(h16, row_start, csr_src, dinv,
                                                      b2b, act16, N);
    }
    // --- layer 4 ---
    gemm_small<<<(N + 255) / 256, 256, 0, stream>>>(act16, W2, dinv, bufC, N, H3);
    agg_f3<<<(N * 3 + 255) / 256, 256, 0, stream>>>(bufC, row_start, csr_src, dinv,
                                                    b2, out, N);
}